// Round 10
// baseline (857.856 us; speedup 1.0000x reference)
//
#include <hip/hip_runtime.h>
#include <stdint.h>

#define BATCH 32
#define SEQ   512
#define DM    512
#define NL    4
#define DSTATE 64
#define DI    1024   // D_INNER
#define NH    16
#define HD    64
#define PREDN 96
#define CDIM  1152   // DI + 2*DSTATE
#define CSEG  144    // CDIM/8
#define DPROJ 2192
#define XBW   1168   // xBC (1152) + dt (16) columns
#define NC    8      // chunks per sequence
#define EPSF  1e-5f

typedef float  f32x4  __attribute__((ext_vector_type(4)));
typedef __bf16 bf16x4 __attribute__((ext_vector_type(4)));
typedef __bf16 bf16x8 __attribute__((ext_vector_type(8)));

__device__ __forceinline__ float sigmoidf_(float x){ return 1.f/(1.f+__expf(-x)); }
__device__ __forceinline__ float siluf_(float x){ return x*sigmoidf_(x); }
__device__ __forceinline__ float softplusf_(float x){ return (x>20.f)?x:log1pf(__expf(x)); }

// direct global->LDS async copy, 16B per lane
__device__ __forceinline__ void gld16(const void* g, void* l){
  __builtin_amdgcn_global_load_lds((__attribute__((address_space(1))) void*)g,
                                   (__attribute__((address_space(3))) void*)l, 16, 0, 0);
}

// ---------------------------------------------------------------------------
// GEMM (B-transposed): bf16 MFMA, 128x128 tile, BK=64, global_load_lds,
// XOR-swizzled LDS (conflict-free), LDS-bounce bf16 epilogue, row-tile-fastest
// grid for XCD A-locality. Split epilogue C/C2. remapA = tail-gather fusion.
// ---------------------------------------------------------------------------
template<typename TC>
__global__ __launch_bounds__(256) void gemm128(
    const __bf16* __restrict__ A, const __bf16* __restrict__ W,
    TC* __restrict__ C, TC* __restrict__ C2, const float* __restrict__ bias,
    int M, int Nreal, int ldc, int ldc2, int splitN, int K, int remapA)
{
  __shared__ __bf16 sAB[2*128*64];
  __bf16* sA = sAB;
  __bf16* sW = sAB + 128*64;
  const int tid  = threadIdx.x;
  const int m0   = blockIdx.x*128, n0 = blockIdx.y*128;
  const int lane = tid&63, wave = tid>>6;
  const int l15  = lane&15, quad = lane>>4;
  const int wr   = (wave>>1)*64, wc = (wave&1)*64;
  f32x4 acc[4][4];
  #pragma unroll
  for (int a=0;a<4;++a)
    #pragma unroll
    for (int b=0;b<4;++b) acc[a][b] = (f32x4){0,0,0,0};

  for (int k0=0; k0<K; k0+=64){
    #pragma unroll
    for (int j=0;j<4;++j){
      const int f = j*256 + tid;
      const int r = f>>3;
      const int kc = (((f&7) ^ (r&7)))*8;
      int ga = m0 + r;
      if (remapA){ int bb = ga/PREDN; ga = bb*SEQ + (SEQ-PREDN) + (ga - bb*PREDN); }
      gld16(A + (size_t)ga*K + k0 + kc, &sA[f*8]);
      int rb = n0 + r; rb = rb < Nreal ? rb : (Nreal-1);
      gld16(W + (size_t)rb*K + k0 + kc, &sW[f*8]);
    }
    __syncthreads();
    #pragma unroll
    for (int kk=0; kk<64; kk+=32){
      const int kcb = (kk>>3) + quad;
      bf16x8 av[4], bv[4];
      #pragma unroll
      for (int mi=0;mi<4;++mi){
        const int row = wr+mi*16+l15;
        av[mi] = *(const bf16x8*)&sA[row*64 + ((kcb ^ (row&7))<<3)];
      }
      #pragma unroll
      for (int ni=0;ni<4;++ni){
        const int row = wc+ni*16+l15;
        bv[ni] = *(const bf16x8*)&sW[row*64 + ((kcb ^ (row&7))<<3)];
      }
      #pragma unroll
      for (int mi=0;mi<4;++mi)
        #pragma unroll
        for (int ni=0;ni<4;++ni)
          acc[mi][ni] = __builtin_amdgcn_mfma_f32_16x16x32_bf16(av[mi],bv[ni],acc[mi][ni],0,0,0);
    }
    __syncthreads();
  }

  if constexpr (sizeof(TC)==2){
    #pragma unroll
    for (int mi=0;mi<4;++mi)
      #pragma unroll
      for (int ni=0;ni<4;++ni)
        #pragma unroll
        for (int r4=0;r4<4;++r4){
          const int row = wr+mi*16+quad*4+r4;
          const int col = wc+ni*16+l15;
          const int g2  = (col>>3) ^ (row&15);
          sAB[row*128 + g2*8 + (col&7)] = (__bf16)acc[mi][ni][r4];
        }
    __syncthreads();
    #pragma unroll
    for (int it=0; it<8; ++it){
      const int idx = it*256 + tid;
      const int row = idx>>4, g = idx&15;
      const int g2 = g ^ (row&15);
      bf16x8 v = *(const bf16x8*)&sAB[row*128 + g2*8];
      const int col0 = n0 + g*8;
      if (col0 < Nreal){
        const int grow = m0 + row;
        if (col0 < splitN) *(bf16x8*)&C [(size_t)grow*ldc  + col0]          = v;
        else               *(bf16x8*)&C2[(size_t)grow*ldc2 + (col0-splitN)] = v;
      }
    }
  } else {
    #pragma unroll
    for (int ni=0;ni<4;++ni){
      const int col = n0 + wc + ni*16 + l15;
      if (col < Nreal){
        const float badd = bias ? bias[col] : 0.f;
        #pragma unroll
        for (int mi=0;mi<4;++mi){
          #pragma unroll
          for (int r4=0;r4<4;++r4){
            const int row = m0 + wr + mi*16 + quad*4 + r4;
            C[(size_t)row*ldc + col] = (TC)(acc[mi][ni][r4] + badd);
          }
        }
      }
    }
  }
}

// ---------------------------------------------------------------------------
// GEMM variant, 64x128 tile, 24 KB LDS: for occupancy-starved shapes
// (out_proj grid 512->1024 blocks, final head 96->192). Same swizzles.
// ---------------------------------------------------------------------------
template<typename TC>
__global__ __launch_bounds__(256) void gemm64(
    const __bf16* __restrict__ A, const __bf16* __restrict__ W,
    TC* __restrict__ C, const float* __restrict__ bias,
    int M, int Nreal, int ldc, int K, int remapA)
{
  __shared__ __bf16 sPool[64*64 + 128*64];   // sA | sW ; epilogue: 64x128 tile
  __bf16* sA = sPool;
  __bf16* sW = sPool + 64*64;
  const int tid  = threadIdx.x;
  const int m0   = blockIdx.x*64, n0 = blockIdx.y*128;
  const int lane = tid&63, wave = tid>>6;
  const int l15  = lane&15, quad = lane>>4;
  const int wr   = (wave&1)*32, wc = (wave>>1)*64;
  f32x4 acc[2][4];
  #pragma unroll
  for (int a=0;a<2;++a)
    #pragma unroll
    for (int b=0;b<4;++b) acc[a][b] = (f32x4){0,0,0,0};

  for (int k0=0; k0<K; k0+=64){
    #pragma unroll
    for (int j=0;j<2;++j){
      const int f = j*256 + tid;
      const int r = f>>3;
      const int kc = (((f&7) ^ (r&7)))*8;
      int ga = m0 + r;
      if (remapA){ int bb = ga/PREDN; ga = bb*SEQ + (SEQ-PREDN) + (ga - bb*PREDN); }
      gld16(A + (size_t)ga*K + k0 + kc, &sA[f*8]);
    }
    #pragma unroll
    for (int j=0;j<4;++j){
      const int f = j*256 + tid;
      const int r = f>>3;
      const int kc = (((f&7) ^ (r&7)))*8;
      int rb = n0 + r; rb = rb < Nreal ? rb : (Nreal-1);
      gld16(W + (size_t)rb*K + k0 + kc, &sW[f*8]);
    }
    __syncthreads();
    #pragma unroll
    for (int kk=0; kk<64; kk+=32){
      const int kcb = (kk>>3) + quad;
      bf16x8 av[2], bv[4];
      #pragma unroll
      for (int mi=0;mi<2;++mi){
        const int row = wr+mi*16+l15;
        av[mi] = *(const bf16x8*)&sA[row*64 + ((kcb ^ (row&7))<<3)];
      }
      #pragma unroll
      for (int ni=0;ni<4;++ni){
        const int row = wc+ni*16+l15;
        bv[ni] = *(const bf16x8*)&sW[row*64 + ((kcb ^ (row&7))<<3)];
      }
      #pragma unroll
      for (int mi=0;mi<2;++mi)
        #pragma unroll
        for (int ni=0;ni<4;++ni)
          acc[mi][ni] = __builtin_amdgcn_mfma_f32_16x16x32_bf16(av[mi],bv[ni],acc[mi][ni],0,0,0);
    }
    __syncthreads();
  }

  if constexpr (sizeof(TC)==2){
    #pragma unroll
    for (int mi=0;mi<2;++mi)
      #pragma unroll
      for (int ni=0;ni<4;++ni)
        #pragma unroll
        for (int r4=0;r4<4;++r4){
          const int row = wr+mi*16+quad*4+r4;
          const int col = wc+ni*16+l15;
          const int g2  = (col>>3) ^ (row&15);
          sPool[row*128 + g2*8 + (col&7)] = (__bf16)acc[mi][ni][r4];
        }
    __syncthreads();
    #pragma unroll
    for (int it=0; it<4; ++it){
      const int idx = it*256 + tid;
      const int row = idx>>4, g = idx&15;
      const int g2 = g ^ (row&15);
      bf16x8 v = *(const bf16x8*)&sPool[row*128 + g2*8];
      const int col0 = n0 + g*8;
      if (col0 < Nreal)
        *(bf16x8*)&C[(size_t)(m0+row)*ldc + col0] = v;
    }
  } else {
    #pragma unroll
    for (int ni=0;ni<4;++ni){
      const int col = n0 + wc + ni*16 + l15;
      if (col < Nreal){
        const float badd = bias ? bias[col] : 0.f;
        #pragma unroll
        for (int mi=0;mi<2;++mi){
          #pragma unroll
          for (int r4=0;r4<4;++r4){
            const int row = m0 + wr + mi*16 + quad*4 + r4;
            C[(size_t)row*ldc + col] = (TC)(acc[mi][ni][r4] + badd);
          }
        }
      }
    }
  }
}

// ---------------------------------------------------------------------------
__global__ __launch_bounds__(256) void cast4_k(
    const float* __restrict__ s0, __bf16* __restrict__ d0, int n0,
    const float* __restrict__ s1, __bf16* __restrict__ d1, int n1,
    const float* __restrict__ s2, __bf16* __restrict__ d2, int n2,
    const float* __restrict__ s3, __bf16* __restrict__ d3, int n3)
{
  int i = blockIdx.x*256 + threadIdx.x;
  const float* s; __bf16* d;
  if (i < n0){ s=s0; d=d0; }
  else if ((i-=n0) < n1){ s=s1; d=d1; }
  else if ((i-=n1) < n2){ s=s2; d=d2; }
  else if ((i-=n2) < n3){ s=s3; d=d3; }
  else return;
  float4 v = ((const float4*)s)[i];
  bf16x4 o;
  o[0]=(__bf16)v.x; o[1]=(__bf16)v.y; o[2]=(__bf16)v.z; o[3]=(__bf16)v.w;
  ((bf16x4*)d)[i] = o;
}

// ---------------------------------------------------------------------------
__global__ __launch_bounds__(256) void conv_silu_k(
    const __bf16* __restrict__ xbw, const float* __restrict__ cw,
    const float* __restrict__ cb, __bf16* __restrict__ xout,
    __bf16* __restrict__ bcout)
{
  int idx = blockIdx.x*256 + threadIdx.x;
  if (idx >= BATCH*SEQ*CSEG) return;
  const int seg = idx % CSEG;
  const int bt  = idx / CSEG;
  const int t = bt % SEQ, b = bt / SEQ;
  const int d0 = seg*8;
  const __bf16* src = xbw + ((size_t)b*SEQ + t)*XBW + d0;
  bf16x8 z8;
  #pragma unroll
  for (int e=0;e<8;++e) z8[e]=(__bf16)0.f;
  bf16x8 x3 = *(const bf16x8*)src;
  bf16x8 x2 = (t>=1)? *(const bf16x8*)(src -   XBW) : z8;
  bf16x8 x1 = (t>=2)? *(const bf16x8*)(src - 2*XBW) : z8;
  bf16x8 x0 = (t>=3)? *(const bf16x8*)(src - 3*XBW) : z8;
  const float4* w4  = (const float4*)(cw + (size_t)d0*4);
  const float4* cb4 = (const float4*)(cb + d0);
  float4 cbl = cb4[0], cbh = cb4[1];
  bf16x8 o;
  #pragma unroll
  for (int e=0;e<8;++e){
    float4 w = w4[e];
    float acc = (e<4 ? (&cbl.x)[e] : (&cbh.x)[e-4])
              + w.x*(float)x0[e] + w.y*(float)x1[e]
              + w.z*(float)x2[e] + w.w*(float)x3[e];
    o[e] = (__bf16)siluf_(acc);
  }
  if (d0 < DI) *(bf16x8*)(xout  + ((size_t)b*SEQ+t)*DI  + d0)       = o;
  else         *(bf16x8*)(bcout + ((size_t)b*SEQ+t)*128 + (d0-DI))  = o;
}

// ---------------------------------------------------------------------------
// Fused SSD: one block per (b,h). R9: 6 distinct LDS buffers (3 barriers per
// chunk — the R8 sS/sB alias added a 4th barrier for zero occupancy gain,
// grid is 2 blocks/CU regardless); register-prefetch of next chunk's bc/x
// rows issued right after the stage barrier -> ~900cyc global latency hides
// behind mm1+mm2.
// ---------------------------------------------------------------------------
__global__ __launch_bounds__(256) void ssd_fused_k(
    const __bf16* __restrict__ bc,
    __bf16* __restrict__ xy,
    const __bf16* __restrict__ xbw,
    const float* __restrict__ dtb_, const float* __restrict__ alog_,
    const float* __restrict__ dp_)
{
  __shared__ __bf16 sB[64*72], sC[64*72], sXT[64*72], sBwT[64*72],
                    sS[64*72], sHT[64*72];
  __shared__ float sCS[SEQ], sDT[SEQ];
  const int bid = blockIdx.x;
  const int h = bid & 15, b = bid >> 4;
  const int tid = threadIdx.x, wave = tid>>6, lane = tid&63;
  const int l15 = lane&15, quad = lane>>4;
  const int wm = (wave>>1)*32, wn = (wave&1)*32;

  const float Ah  = -__expf(alog_[h]);
  const float dtb = dtb_[h];
  const float Dh  = dp_[h];

  for (int t = tid; t < SEQ; t += 256){
    float raw = (float)xbw[((size_t)b*SEQ + t)*XBW + CDIM + h];
    float dt = softplusf_(raw + dtb);
    sDT[t] = dt;
    sCS[t] = dt*Ah;
  }
  __syncthreads();
  for (int ch = wave; ch < NC; ch += 4){
    float s = sCS[ch*64 + lane];
    #pragma unroll
    for (int off=1; off<64; off<<=1){
      float v = __shfl_up(s, off);
      if (lane >= off) s += v;
    }
    sCS[ch*64 + lane] = s;
  }
  __syncthreads();

  f32x4 run[2][2];
  #pragma unroll
  for (int a=0;a<2;++a)
    #pragma unroll
    for (int d=0;d<2;++d) run[a][d] = (f32x4){0,0,0,0};

  const int r = tid>>2, seg = (tid&3)*16;
  // prefetch chunk 0
  bf16x8 pb0, pb1, pc0, pc1, px0, px1;
  {
    const __bf16* row = bc + ((size_t)b*SEQ + r)*128;
    pb0 = *(const bf16x8*)(row + seg);
    pb1 = *(const bf16x8*)(row + seg + 8);
    pc0 = *(const bf16x8*)(row + 64 + seg);
    pc1 = *(const bf16x8*)(row + 64 + seg + 8);
    const __bf16* xrow = xy + ((size_t)b*SEQ + r)*DI + h*64;
    px0 = *(const bf16x8*)(xrow + seg);
    px1 = *(const bf16x8*)(xrow + seg + 8);
  }

  for (int c = 0; c < NC; ++c){
    const int t0 = c*64;
    // ---- write prefetched regs to LDS (incl. transposes) ----
    {
      *(bf16x8*)&sB[r*72+seg]   = pb0;
      *(bf16x8*)&sB[r*72+seg+8] = pb1;
      *(bf16x8*)&sC[r*72+seg]   = pc0;
      *(bf16x8*)&sC[r*72+seg+8] = pc1;
      const float w = __expf(sCS[t0+63] - sCS[t0+r]) * sDT[t0+r];  // <=0 exp
      #pragma unroll
      for (int e=0;e<8;++e){
        sBwT[(seg+e)*72 + r]   = (__bf16)(w*(float)pb0[e]);
        sBwT[(seg+8+e)*72 + r] = (__bf16)(w*(float)pb1[e]);
        sXT[(seg+e)*72 + r]    = px0[e];
        sXT[(seg+8+e)*72 + r]  = px1[e];
      }
    }
    __syncthreads();
    // ---- issue next chunk's prefetch (consumed at next iter's LDS write) ----
    if (c+1 < NC){
      const __bf16* row = bc + ((size_t)b*SEQ + t0 + 64 + r)*128;
      pb0 = *(const bf16x8*)(row + seg);
      pb1 = *(const bf16x8*)(row + seg + 8);
      pc0 = *(const bf16x8*)(row + 64 + seg);
      pc1 = *(const bf16x8*)(row + 64 + seg + 8);
      const __bf16* xrow = xy + ((size_t)b*SEQ + t0 + 64 + r)*DI + h*64;
      px0 = *(const bf16x8*)(xrow + seg);
      px1 = *(const bf16x8*)(xrow + seg + 8);
    }

    // ---- mm1: S[i][j] = sum_n C[i,n]*B[j,n] ----
    f32x4 aS[2][2];
    #pragma unroll
    for (int a=0;a<2;++a)
      #pragma unroll
      for (int d=0;d<2;++d) aS[a][d] = (f32x4){0,0,0,0};
    #pragma unroll
    for (int kk=0; kk<64; kk+=32){
      const int kf = kk + quad*8;
      bf16x8 a0 = *(const bf16x8*)&sC[(wm+l15)*72+kf];
      bf16x8 a1 = *(const bf16x8*)&sC[(wm+16+l15)*72+kf];
      bf16x8 b0 = *(const bf16x8*)&sB[(wn+l15)*72+kf];
      bf16x8 b1 = *(const bf16x8*)&sB[(wn+16+l15)*72+kf];
      aS[0][0] = __builtin_amdgcn_mfma_f32_16x16x32_bf16(a0,b0,aS[0][0],0,0,0);
      aS[0][1] = __builtin_amdgcn_mfma_f32_16x16x32_bf16(a0,b1,aS[0][1],0,0,0);
      aS[1][0] = __builtin_amdgcn_mfma_f32_16x16x32_bf16(a1,b0,aS[1][0],0,0,0);
      aS[1][1] = __builtin_amdgcn_mfma_f32_16x16x32_bf16(a1,b1,aS[1][1],0,0,0);
    }
    // mask + decay -> sS; dump current run -> sHT (distinct buffers, no
    // barrier needed before these writes)
    #pragma unroll
    for (int mi=0;mi<2;++mi)
      #pragma unroll
      for (int ni=0;ni<2;++ni)
        #pragma unroll
        for (int r4=0;r4<4;++r4){
          const int i = wm+mi*16+quad*4+r4, j = wn+ni*16+l15;
          float ed = __expf(fminf(sCS[t0+i]-sCS[t0+j], 0.f)) * sDT[t0+j];
          float v = aS[mi][ni][r4]*ed;
          sS[i*72+j] = (__bf16)((j<=i)? v : 0.f);
          sHT[j*72+i] = (__bf16)run[mi][ni][r4];   // [p][n]
        }
    __syncthreads();

    // ---- mm2: Y_intra = S@X, H = Bw^T@X, Y_inter = Cc@run^T ----
    f32x4 aY[2][2], aH[2][2], aYi[2][2];
    #pragma unroll
    for (int a=0;a<2;++a)
      #pragma unroll
      for (int d=0;d<2;++d){
        aY[a][d]=(f32x4){0,0,0,0}; aH[a][d]=(f32x4){0,0,0,0};
        aYi[a][d]=(f32x4){0,0,0,0};
      }
    #pragma unroll
    for (int kk=0; kk<64; kk+=32){
      const int kf = kk + quad*8;
      bf16x8 b0 = *(const bf16x8*)&sXT[(wn+l15)*72+kf];
      bf16x8 b1 = *(const bf16x8*)&sXT[(wn+16+l15)*72+kf];
      bf16x8 s0 = *(const bf16x8*)&sS[(wm+l15)*72+kf];
      bf16x8 s1 = *(const bf16x8*)&sS[(wm+16+l15)*72+kf];
      bf16x8 w0 = *(const bf16x8*)&sBwT[(wm+l15)*72+kf];
      bf16x8 w1 = *(const bf16x8*)&sBwT[(wm+16+l15)*72+kf];
      bf16x8 c0 = *(const bf16x8*)&sC[(wm+l15)*72+kf];
      bf16x8 c1 = *(const bf16x8*)&sC[(wm+16+l15)*72+kf];
      bf16x8 h0 = *(const bf16x8*)&sHT[(wn+l15)*72+kf];
      bf16x8 h1 = *(const bf16x8*)&sHT[(wn+16+l15)*72+kf];
      aY[0][0] = __builtin_amdgcn_mfma_f32_16x16x32_bf16(s0,b0,aY[0][0],0,0,0);
      aY[0][1] = __builtin_amdgcn_mfma_f32_16x16x32_bf16(s0,b1,aY[0][1],0,0,0);
      aY[1][0] = __builtin_amdgcn_mfma_f32_16x16x32_bf16(s1,b0,aY[1][0],0,0,0);
      aY[1][1] = __builtin_amdgcn_mfma_f32_16x16x32_bf16(s1,b1,aY[1][1],0,0,0);
      aH[0][0] = __builtin_amdgcn_mfma_f32_16x16x32_bf16(w0,b0,aH[0][0],0,0,0);
      aH[0][1] = __builtin_amdgcn_mfma_f32_16x16x32_bf16(w0,b1,aH[0][1],0,0,0);
      aH[1][0] = __builtin_amdgcn_mfma_f32_16x16x32_bf16(w1,b0,aH[1][0],0,0,0);
      aH[1][1] = __builtin_amdgcn_mfma_f32_16x16x32_bf16(w1,b1,aH[1][1],0,0,0);
      aYi[0][0] = __builtin_amdgcn_mfma_f32_16x16x32_bf16(c0,h0,aYi[0][0],0,0,0);
      aYi[0][1] = __builtin_amdgcn_mfma_f32_16x16x32_bf16(c0,h1,aYi[0][1],0,0,0);
      aYi[1][0] = __builtin_amdgcn_mfma_f32_16x16x32_bf16(c1,h0,aYi[1][0],0,0,0);
      aYi[1][1] = __builtin_amdgcn_mfma_f32_16x16x32_bf16(c1,h1,aYi[1][1],0,0,0);
    }

    const float lam = __expf(sCS[t0+63]);
    #pragma unroll
    for (int mi=0;mi<2;++mi)
      #pragma unroll
      for (int ni=0;ni<2;++ni)
        #pragma unroll
        for (int r4=0;r4<4;++r4){
          const int i = wm+mi*16+quad*4+r4;
          const int p = wn+ni*16+l15;
          const float xval = (float)sXT[p*72 + i];
          const float e2 = __expf(sCS[t0+i]);    // <=1 (cs<=0)
          const float yv = aY[mi][ni][r4] + Dh*xval + e2*aYi[mi][ni][r4];
          xy[((size_t)b*SEQ + t0 + i)*DI + h*64 + p] = (__bf16)yv;
          run[mi][ni][r4] = run[mi][ni][r4]*lam + aH[mi][ni][r4];
        }
    __syncthreads();
  }
}

// ---------------------------------------------------------------------------
__global__ __launch_bounds__(256) void gate_rms_k(
    __bf16* __restrict__ y, const __bf16* __restrict__ z, const float* __restrict__ nw)
{
  __shared__ float red[4];
  const int tid = threadIdx.x;
  const int sub = tid>>7;
  const int off = (tid&127)*8;
  const size_t row = (size_t)blockIdx.x*2 + sub;
  __bf16* yrow = y + row*DI;
  const __bf16* zrow = z + row*DI;
  bf16x8 yv = *(const bf16x8*)(yrow+off);
  bf16x8 zv = *(const bf16x8*)(zrow+off);
  float u[8]; float ss = 0.f;
  #pragma unroll
  for (int e=0;e<8;++e){
    float uu = (float)yv[e]*siluf_((float)zv[e]);
    u[e]=uu; ss += uu*uu;
  }
  #pragma unroll
  for (int o=32;o;o>>=1) ss += __shfl_xor(ss,o);
  if ((tid&63)==0) red[tid>>6] = ss;
  __syncthreads();
  ss = red[sub*2] + red[sub*2+1];
  const float sc = rsqrtf(ss*(1.f/DI) + EPSF);
  const float4* nw4 = (const float4*)(nw + off);
  float4 n0 = nw4[0], n1 = nw4[1];
  bf16x8 o;
  #pragma unroll
  for (int e=0;e<8;++e)
    o[e] = (__bf16)(u[e]*sc*(e<4 ? (&n0.x)[e] : (&n1.x)[e-4]));
  *(bf16x8*)(yrow+off) = o;
}

// ---------------------------------------------------------------------------
__global__ __launch_bounds__(256) void add_ln_k(
    const __bf16* __restrict__ tmp, __bf16* __restrict__ resio,
    const float* __restrict__ w, const float* __restrict__ bb)
{
  const int tid = threadIdx.x, lane = tid&63;
  const size_t row = (size_t)blockIdx.x*4 + (tid>>6);
  const int off = lane*8;
  const __bf16* trow = tmp + row*DM;
  __bf16* rrow = resio + row*DM;
  bf16x8 tv = *(const bf16x8*)(trow+off);
  bf16x8 rv = *(const bf16x8*)(rrow+off);
  float v[8]; float s = 0.f;
  #pragma unroll
  for (int e=0;e<8;++e){ v[e]=(float)tv[e]+(float)rv[e]; s += v[e]; }
  #pragma unroll
  for (int o=32;o;o>>=1) s += __shfl_xor(s,o);
  const float mean = s*(1.f/DM);
  float q = 0.f;
  #pragma unroll
  for (int e=0;e<8;++e){ v[e]-=mean; q += v[e]*v[e]; }
  #pragma unroll
  for (int o=32;o;o>>=1) q += __shfl_xor(q,o);
  const float rstd = rsqrtf(q*(1.f/DM) + EPSF);
  const float4* w4 = (const float4*)(w + off);
  const float4* b4 = (const float4*)(bb + off);
  float4 w0=w4[0], w1=w4[1], b0=b4[0], b1=b4[1];
  bf16x8 o8;
  #pragma unroll
  for (int e=0;e<8;++e){
    float we = e<4 ? (&w0.x)[e] : (&w1.x)[e-4];
    float be = e<4 ? (&b0.x)[e] : (&b1.x)[e-4];
    o8[e] = (__bf16)(v[e]*rstd*we + be);
  }
  *(bf16x8*)(rrow+off) = o8;
}

// ---------------------------------------------------------------------------
extern "C" void kernel_launch(void* const* d_in, const int* in_sizes, int n_in,
                              void* d_out, int out_size, void* d_ws, size_t ws_size,
                              hipStream_t stream)
{
  const float* x         = (const float*)d_in[0];
  const float* in_proj_w = (const float*)d_in[1];
  const float* conv_w    = (const float*)d_in[2];
  const float* conv_b    = (const float*)d_in[3];
  const float* dt_bias   = (const float*)d_in[4];
  const float* A_log     = (const float*)d_in[5];
  const float* Dp        = (const float*)d_in[6];
  const float* norm_w    = (const float*)d_in[7];
  const float* out_proj_w= (const float*)d_in[8];
  const float* ln_w      = (const float*)d_in[9];
  const float* ln_b      = (const float*)d_in[10];
  const float* final_w   = (const float*)d_in[11];
  const float* final_b   = (const float*)d_in[12];
  float* out = (float*)d_out;

  const size_t ROWS = (size_t)BATCH*SEQ;        // 16384
  __bf16* wbf_in  = (__bf16*)d_ws;
  __bf16* wbf_out = wbf_in  + (size_t)NL*DPROJ*DM;
  __bf16* wbf_fin = wbf_out + (size_t)NL*DM*DI;
  __bf16* zbuf    = wbf_fin + (size_t)DM*DM;
  __bf16* xbw     = zbuf    + ROWS*DI;
  __bf16* ybuf    = xbw     + ROWS*XBW;
  __bf16* bcb     = ybuf    + ROWS*DI;
  __bf16* xcur    = bcb     + ROWS*128;
  __bf16* tmp  = xbw;     // alias: xbw dead after ssd_fused reads dt

  {
    int n1 = NL*DPROJ*DM/4, n2 = NL*DM*DI/4, n3 = DM*DM/4, n4 = (int)(ROWS*DM/4);
    int tot = n1+n2+n3+n4;
    cast4_k<<<(tot+255)/256, 256, 0, stream>>>(
        in_proj_w, wbf_in, n1, out_proj_w, wbf_out, n2,
        final_w, wbf_fin, n3, x, xcur, n4);
  }

  const int convTotal = BATCH*SEQ*CSEG;

  for (int l=0; l<NL; ++l){
    const __bf16* wl = wbf_in + (size_t)l*DPROJ*DM;
    // in_proj: grid x = row-tile (XCD A-locality), y = col-tile
    gemm128<__bf16><<<dim3((int)(ROWS/128), (DPROJ+127)/128), 256, 0, stream>>>(
        xcur, wl, zbuf, xbw, nullptr, (int)ROWS, DPROJ, DI, XBW, DI, DM, 0);
    conv_silu_k<<<(convTotal+255)/256, 256, 0, stream>>>(
        xbw, conv_w + (size_t)l*CDIM*4, conv_b + (size_t)l*CDIM, ybuf, bcb);
    ssd_fused_k<<<BATCH*NH, 256, 0, stream>>>(
        bcb, ybuf, xbw, dt_bias + l*NH, A_log + l*NH, Dp + l*NH);
    gate_rms_k<<<(int)(ROWS/2), 256, 0, stream>>>(ybuf, zbuf, norm_w + (size_t)l*DI);
    // out_proj: 64-row tiles -> 1024 blocks (4/CU)
    gemm64<__bf16><<<dim3((int)(ROWS/64), DM/128), 256, 0, stream>>>(
        ybuf, wbf_out + (size_t)l*DM*DI, tmp, nullptr, (int)ROWS, DM, DM, DI, 0);
    add_ln_k<<<(int)(ROWS/4), 256, 0, stream>>>(tmp, xcur, ln_w + l*DM, ln_b + l*DM);
  }
  // final head: 64-row tiles, A-rows remapped to last PREDN timesteps
  gemm64<float><<<dim3((BATCH*PREDN)/64, DM/128), 256, 0, stream>>>(
      xcur, wbf_fin, out, final_b, BATCH*PREDN, DM, DM, DM, 1);
}

// Round 11
// 840.767 us; speedup vs baseline: 1.0203x; 1.0203x over previous
//
#include <hip/hip_runtime.h>
#include <stdint.h>

#define BATCH 32
#define SEQ   512
#define DM    512
#define NL    4
#define DSTATE 64
#define DI    1024   // D_INNER
#define NH    16
#define HD    64
#define PREDN 96
#define CDIM  1152   // DI + 2*DSTATE
#define CSEG  144    // CDIM/8
#define DPROJ 2192
#define XBW   1168   // xBC (1152) + dt (16) columns
#define NC    8      // chunks per sequence
#define EPSF  1e-5f

typedef float  f32x4  __attribute__((ext_vector_type(4)));
typedef __bf16 bf16x4 __attribute__((ext_vector_type(4)));
typedef __bf16 bf16x8 __attribute__((ext_vector_type(8)));

__device__ __forceinline__ float sigmoidf_(float x){ return 1.f/(1.f+__expf(-x)); }
__device__ __forceinline__ float siluf_(float x){ return x*sigmoidf_(x); }
__device__ __forceinline__ float softplusf_(float x){ return (x>20.f)?x:log1pf(__expf(x)); }

// direct global->LDS async copy, 16B per lane
__device__ __forceinline__ void gld16(const void* g, void* l){
  __builtin_amdgcn_global_load_lds((__attribute__((address_space(1))) void*)g,
                                   (__attribute__((address_space(3))) void*)l, 16, 0, 0);
}

// ---------------------------------------------------------------------------
// GEMM (B-transposed): bf16 MFMA, 128x128 tile, BK=64, global_load_lds,
// XOR-swizzled LDS (conflict-free), LDS-bounce bf16 epilogue, row-tile-fastest
// grid for XCD A-locality. Split epilogue C/C2. remapA = tail-gather fusion.
// R10 lesson: 64-row tiles regress (1.5x staging instr per output on a
// VALU-bound structure) — keep 128x128 for ALL shapes.
// ---------------------------------------------------------------------------
template<typename TC>
__global__ __launch_bounds__(256) void gemm128(
    const __bf16* __restrict__ A, const __bf16* __restrict__ W,
    TC* __restrict__ C, TC* __restrict__ C2, const float* __restrict__ bias,
    int M, int Nreal, int ldc, int ldc2, int splitN, int K, int remapA)
{
  __shared__ __bf16 sAB[2*128*64];
  __bf16* sA = sAB;
  __bf16* sW = sAB + 128*64;
  const int tid  = threadIdx.x;
  const int m0   = blockIdx.x*128, n0 = blockIdx.y*128;
  const int lane = tid&63, wave = tid>>6;
  const int l15  = lane&15, quad = lane>>4;
  const int wr   = (wave>>1)*64, wc = (wave&1)*64;
  f32x4 acc[4][4];
  #pragma unroll
  for (int a=0;a<4;++a)
    #pragma unroll
    for (int b=0;b<4;++b) acc[a][b] = (f32x4){0,0,0,0};

  for (int k0=0; k0<K; k0+=64){
    #pragma unroll
    for (int j=0;j<4;++j){
      const int f = j*256 + tid;
      const int r = f>>3;
      const int kc = (((f&7) ^ (r&7)))*8;
      int ga = m0 + r;
      if (remapA){ int bb = ga/PREDN; ga = bb*SEQ + (SEQ-PREDN) + (ga - bb*PREDN); }
      gld16(A + (size_t)ga*K + k0 + kc, &sA[f*8]);
      int rb = n0 + r; rb = rb < Nreal ? rb : (Nreal-1);
      gld16(W + (size_t)rb*K + k0 + kc, &sW[f*8]);
    }
    __syncthreads();
    #pragma unroll
    for (int kk=0; kk<64; kk+=32){
      const int kcb = (kk>>3) + quad;
      bf16x8 av[4], bv[4];
      #pragma unroll
      for (int mi=0;mi<4;++mi){
        const int row = wr+mi*16+l15;
        av[mi] = *(const bf16x8*)&sA[row*64 + ((kcb ^ (row&7))<<3)];
      }
      #pragma unroll
      for (int ni=0;ni<4;++ni){
        const int row = wc+ni*16+l15;
        bv[ni] = *(const bf16x8*)&sW[row*64 + ((kcb ^ (row&7))<<3)];
      }
      #pragma unroll
      for (int mi=0;mi<4;++mi)
        #pragma unroll
        for (int ni=0;ni<4;++ni)
          acc[mi][ni] = __builtin_amdgcn_mfma_f32_16x16x32_bf16(av[mi],bv[ni],acc[mi][ni],0,0,0);
    }
    __syncthreads();
  }

  if constexpr (sizeof(TC)==2){
    #pragma unroll
    for (int mi=0;mi<4;++mi)
      #pragma unroll
      for (int ni=0;ni<4;++ni)
        #pragma unroll
        for (int r4=0;r4<4;++r4){
          const int row = wr+mi*16+quad*4+r4;
          const int col = wc+ni*16+l15;
          const int g2  = (col>>3) ^ (row&15);
          sAB[row*128 + g2*8 + (col&7)] = (__bf16)acc[mi][ni][r4];
        }
    __syncthreads();
    #pragma unroll
    for (int it=0; it<8; ++it){
      const int idx = it*256 + tid;
      const int row = idx>>4, g = idx&15;
      const int g2 = g ^ (row&15);
      bf16x8 v = *(const bf16x8*)&sAB[row*128 + g2*8];
      const int col0 = n0 + g*8;
      if (col0 < Nreal){
        const int grow = m0 + row;
        if (col0 < splitN) *(bf16x8*)&C [(size_t)grow*ldc  + col0]          = v;
        else               *(bf16x8*)&C2[(size_t)grow*ldc2 + (col0-splitN)] = v;
      }
    }
  } else {
    #pragma unroll
    for (int ni=0;ni<4;++ni){
      const int col = n0 + wc + ni*16 + l15;
      if (col < Nreal){
        const float badd = bias ? bias[col] : 0.f;
        #pragma unroll
        for (int mi=0;mi<4;++mi){
          #pragma unroll
          for (int r4=0;r4<4;++r4){
            const int row = m0 + wr + mi*16 + quad*4 + r4;
            C[(size_t)row*ldc + col] = (TC)(acc[mi][ni][r4] + badd);
          }
        }
      }
    }
  }
}

// ---------------------------------------------------------------------------
__global__ __launch_bounds__(256) void cast4_k(
    const float* __restrict__ s0, __bf16* __restrict__ d0, int n0,
    const float* __restrict__ s1, __bf16* __restrict__ d1, int n1,
    const float* __restrict__ s2, __bf16* __restrict__ d2, int n2,
    const float* __restrict__ s3, __bf16* __restrict__ d3, int n3)
{
  int i = blockIdx.x*256 + threadIdx.x;
  const float* s; __bf16* d;
  if (i < n0){ s=s0; d=d0; }
  else if ((i-=n0) < n1){ s=s1; d=d1; }
  else if ((i-=n1) < n2){ s=s2; d=d2; }
  else if ((i-=n2) < n3){ s=s3; d=d3; }
  else return;
  float4 v = ((const float4*)s)[i];
  bf16x4 o;
  o[0]=(__bf16)v.x; o[1]=(__bf16)v.y; o[2]=(__bf16)v.z; o[3]=(__bf16)v.w;
  ((bf16x4*)d)[i] = o;
}

// ---------------------------------------------------------------------------
__global__ __launch_bounds__(256) void conv_silu_k(
    const __bf16* __restrict__ xbw, const float* __restrict__ cw,
    const float* __restrict__ cb, __bf16* __restrict__ xout,
    __bf16* __restrict__ bcout)
{
  int idx = blockIdx.x*256 + threadIdx.x;
  if (idx >= BATCH*SEQ*CSEG) return;
  const int seg = idx % CSEG;
  const int bt  = idx / CSEG;
  const int t = bt % SEQ, b = bt / SEQ;
  const int d0 = seg*8;
  const __bf16* src = xbw + ((size_t)b*SEQ + t)*XBW + d0;
  bf16x8 z8;
  #pragma unroll
  for (int e=0;e<8;++e) z8[e]=(__bf16)0.f;
  bf16x8 x3 = *(const bf16x8*)src;
  bf16x8 x2 = (t>=1)? *(const bf16x8*)(src -   XBW) : z8;
  bf16x8 x1 = (t>=2)? *(const bf16x8*)(src - 2*XBW) : z8;
  bf16x8 x0 = (t>=3)? *(const bf16x8*)(src - 3*XBW) : z8;
  const float4* w4  = (const float4*)(cw + (size_t)d0*4);
  const float4* cb4 = (const float4*)(cb + d0);
  float4 cbl = cb4[0], cbh = cb4[1];
  bf16x8 o;
  #pragma unroll
  for (int e=0;e<8;++e){
    float4 w = w4[e];
    float acc = (e<4 ? (&cbl.x)[e] : (&cbh.x)[e-4])
              + w.x*(float)x0[e] + w.y*(float)x1[e]
              + w.z*(float)x2[e] + w.w*(float)x3[e];
    o[e] = (__bf16)siluf_(acc);
  }
  if (d0 < DI) *(bf16x8*)(xout  + ((size_t)b*SEQ+t)*DI  + d0)       = o;
  else         *(bf16x8*)(bcout + ((size_t)b*SEQ+t)*128 + (d0-DI))  = o;
}

// ---------------------------------------------------------------------------
// Fused SSD: one block per (b,h). 6 distinct LDS buffers (3 barriers/chunk) +
// register-prefetch of next chunk's bc/x rows (issued after the stage barrier,
// consumed at next iter's LDS write — hides ~900cyc global latency behind
// mm1+mm2 at 2 blocks/CU).
// ---------------------------------------------------------------------------
__global__ __launch_bounds__(256) void ssd_fused_k(
    const __bf16* __restrict__ bc,
    __bf16* __restrict__ xy,
    const __bf16* __restrict__ xbw,
    const float* __restrict__ dtb_, const float* __restrict__ alog_,
    const float* __restrict__ dp_)
{
  __shared__ __bf16 sB[64*72], sC[64*72], sXT[64*72], sBwT[64*72],
                    sS[64*72], sHT[64*72];
  __shared__ float sCS[SEQ], sDT[SEQ];
  const int bid = blockIdx.x;
  const int h = bid & 15, b = bid >> 4;
  const int tid = threadIdx.x, wave = tid>>6, lane = tid&63;
  const int l15 = lane&15, quad = lane>>4;
  const int wm = (wave>>1)*32, wn = (wave&1)*32;

  const float Ah  = -__expf(alog_[h]);
  const float dtb = dtb_[h];
  const float Dh  = dp_[h];

  for (int t = tid; t < SEQ; t += 256){
    float raw = (float)xbw[((size_t)b*SEQ + t)*XBW + CDIM + h];
    float dt = softplusf_(raw + dtb);
    sDT[t] = dt;
    sCS[t] = dt*Ah;
  }
  __syncthreads();
  for (int ch = wave; ch < NC; ch += 4){
    float s = sCS[ch*64 + lane];
    #pragma unroll
    for (int off=1; off<64; off<<=1){
      float v = __shfl_up(s, off);
      if (lane >= off) s += v;
    }
    sCS[ch*64 + lane] = s;
  }
  __syncthreads();

  f32x4 run[2][2];
  #pragma unroll
  for (int a=0;a<2;++a)
    #pragma unroll
    for (int d=0;d<2;++d) run[a][d] = (f32x4){0,0,0,0};

  const int r = tid>>2, seg = (tid&3)*16;
  // prefetch chunk 0
  bf16x8 pb0, pb1, pc0, pc1, px0, px1;
  {
    const __bf16* row = bc + ((size_t)b*SEQ + r)*128;
    pb0 = *(const bf16x8*)(row + seg);
    pb1 = *(const bf16x8*)(row + seg + 8);
    pc0 = *(const bf16x8*)(row + 64 + seg);
    pc1 = *(const bf16x8*)(row + 64 + seg + 8);
    const __bf16* xrow = xy + ((size_t)b*SEQ + r)*DI + h*64;
    px0 = *(const bf16x8*)(xrow + seg);
    px1 = *(const bf16x8*)(xrow + seg + 8);
  }

  for (int c = 0; c < NC; ++c){
    const int t0 = c*64;
    // ---- write prefetched regs to LDS (incl. transposes) ----
    {
      *(bf16x8*)&sB[r*72+seg]   = pb0;
      *(bf16x8*)&sB[r*72+seg+8] = pb1;
      *(bf16x8*)&sC[r*72+seg]   = pc0;
      *(bf16x8*)&sC[r*72+seg+8] = pc1;
      const float w = __expf(sCS[t0+63] - sCS[t0+r]) * sDT[t0+r];  // <=0 exp
      #pragma unroll
      for (int e=0;e<8;++e){
        sBwT[(seg+e)*72 + r]   = (__bf16)(w*(float)pb0[e]);
        sBwT[(seg+8+e)*72 + r] = (__bf16)(w*(float)pb1[e]);
        sXT[(seg+e)*72 + r]    = px0[e];
        sXT[(seg+8+e)*72 + r]  = px1[e];
      }
    }
    __syncthreads();
    // ---- issue next chunk's prefetch ----
    if (c+1 < NC){
      const __bf16* row = bc + ((size_t)b*SEQ + t0 + 64 + r)*128;
      pb0 = *(const bf16x8*)(row + seg);
      pb1 = *(const bf16x8*)(row + seg + 8);
      pc0 = *(const bf16x8*)(row + 64 + seg);
      pc1 = *(const bf16x8*)(row + 64 + seg + 8);
      const __bf16* xrow = xy + ((size_t)b*SEQ + t0 + 64 + r)*DI + h*64;
      px0 = *(const bf16x8*)(xrow + seg);
      px1 = *(const bf16x8*)(xrow + seg + 8);
    }

    // ---- mm1: S[i][j] = sum_n C[i,n]*B[j,n] ----
    f32x4 aS[2][2];
    #pragma unroll
    for (int a=0;a<2;++a)
      #pragma unroll
      for (int d=0;d<2;++d) aS[a][d] = (f32x4){0,0,0,0};
    #pragma unroll
    for (int kk=0; kk<64; kk+=32){
      const int kf = kk + quad*8;
      bf16x8 a0 = *(const bf16x8*)&sC[(wm+l15)*72+kf];
      bf16x8 a1 = *(const bf16x8*)&sC[(wm+16+l15)*72+kf];
      bf16x8 b0 = *(const bf16x8*)&sB[(wn+l15)*72+kf];
      bf16x8 b1 = *(const bf16x8*)&sB[(wn+16+l15)*72+kf];
      aS[0][0] = __builtin_amdgcn_mfma_f32_16x16x32_bf16(a0,b0,aS[0][0],0,0,0);
      aS[0][1] = __builtin_amdgcn_mfma_f32_16x16x32_bf16(a0,b1,aS[0][1],0,0,0);
      aS[1][0] = __builtin_amdgcn_mfma_f32_16x16x32_bf16(a1,b0,aS[1][0],0,0,0);
      aS[1][1] = __builtin_amdgcn_mfma_f32_16x16x32_bf16(a1,b1,aS[1][1],0,0,0);
    }
    // mask + decay -> sS; dump current run -> sHT (distinct buffers)
    #pragma unroll
    for (int mi=0;mi<2;++mi)
      #pragma unroll
      for (int ni=0;ni<2;++ni)
        #pragma unroll
        for (int r4=0;r4<4;++r4){
          const int i = wm+mi*16+quad*4+r4, j = wn+ni*16+l15;
          float ed = __expf(fminf(sCS[t0+i]-sCS[t0+j], 0.f)) * sDT[t0+j];
          float v = aS[mi][ni][r4]*ed;
          sS[i*72+j] = (__bf16)((j<=i)? v : 0.f);
          sHT[j*72+i] = (__bf16)run[mi][ni][r4];   // [p][n]
        }
    __syncthreads();

    // ---- mm2: Y_intra = S@X, H = Bw^T@X, Y_inter = Cc@run^T ----
    f32x4 aY[2][2], aH[2][2], aYi[2][2];
    #pragma unroll
    for (int a=0;a<2;++a)
      #pragma unroll
      for (int d=0;d<2;++d){
        aY[a][d]=(f32x4){0,0,0,0}; aH[a][d]=(f32x4){0,0,0,0};
        aYi[a][d]=(f32x4){0,0,0,0};
      }
    #pragma unroll
    for (int kk=0; kk<64; kk+=32){
      const int kf = kk + quad*8;
      bf16x8 b0 = *(const bf16x8*)&sXT[(wn+l15)*72+kf];
      bf16x8 b1 = *(const bf16x8*)&sXT[(wn+16+l15)*72+kf];
      bf16x8 s0 = *(const bf16x8*)&sS[(wm+l15)*72+kf];
      bf16x8 s1 = *(const bf16x8*)&sS[(wm+16+l15)*72+kf];
      bf16x8 w0 = *(const bf16x8*)&sBwT[(wm+l15)*72+kf];
      bf16x8 w1 = *(const bf16x8*)&sBwT[(wm+16+l15)*72+kf];
      bf16x8 c0 = *(const bf16x8*)&sC[(wm+l15)*72+kf];
      bf16x8 c1 = *(const bf16x8*)&sC[(wm+16+l15)*72+kf];
      bf16x8 h0 = *(const bf16x8*)&sHT[(wn+l15)*72+kf];
      bf16x8 h1 = *(const bf16x8*)&sHT[(wn+16+l15)*72+kf];
      aY[0][0] = __builtin_amdgcn_mfma_f32_16x16x32_bf16(s0,b0,aY[0][0],0,0,0);
      aY[0][1] = __builtin_amdgcn_mfma_f32_16x16x32_bf16(s0,b1,aY[0][1],0,0,0);
      aY[1][0] = __builtin_amdgcn_mfma_f32_16x16x32_bf16(s1,b0,aY[1][0],0,0,0);
      aY[1][1] = __builtin_amdgcn_mfma_f32_16x16x32_bf16(s1,b1,aY[1][1],0,0,0);
      aH[0][0] = __builtin_amdgcn_mfma_f32_16x16x32_bf16(w0,b0,aH[0][0],0,0,0);
      aH[0][1] = __builtin_amdgcn_mfma_f32_16x16x32_bf16(w0,b1,aH[0][1],0,0,0);
      aH[1][0] = __builtin_amdgcn_mfma_f32_16x16x32_bf16(w1,b0,aH[1][0],0,0,0);
      aH[1][1] = __builtin_amdgcn_mfma_f32_16x16x32_bf16(w1,b1,aH[1][1],0,0,0);
      aYi[0][0] = __builtin_amdgcn_mfma_f32_16x16x32_bf16(c0,h0,aYi[0][0],0,0,0);
      aYi[0][1] = __builtin_amdgcn_mfma_f32_16x16x32_bf16(c0,h1,aYi[0][1],0,0,0);
      aYi[1][0] = __builtin_amdgcn_mfma_f32_16x16x32_bf16(c1,h0,aYi[1][0],0,0,0);
      aYi[1][1] = __builtin_amdgcn_mfma_f32_16x16x32_bf16(c1,h1,aYi[1][1],0,0,0);
    }

    const float lam = __expf(sCS[t0+63]);
    #pragma unroll
    for (int mi=0;mi<2;++mi)
      #pragma unroll
      for (int ni=0;ni<2;++ni)
        #pragma unroll
        for (int r4=0;r4<4;++r4){
          const int i = wm+mi*16+quad*4+r4;
          const int p = wn+ni*16+l15;
          const float xval = (float)sXT[p*72 + i];
          const float e2 = __expf(sCS[t0+i]);    // <=1 (cs<=0)
          const float yv = aY[mi][ni][r4] + Dh*xval + e2*aYi[mi][ni][r4];
          xy[((size_t)b*SEQ + t0 + i)*DI + h*64 + p] = (__bf16)yv;
          run[mi][ni][r4] = run[mi][ni][r4]*lam + aH[mi][ni][r4];
        }
    __syncthreads();
  }
}

// ---------------------------------------------------------------------------
__global__ __launch_bounds__(256) void gate_rms_k(
    __bf16* __restrict__ y, const __bf16* __restrict__ z, const float* __restrict__ nw)
{
  __shared__ float red[4];
  const int tid = threadIdx.x;
  const int sub = tid>>7;
  const int off = (tid&127)*8;
  const size_t row = (size_t)blockIdx.x*2 + sub;
  __bf16* yrow = y + row*DI;
  const __bf16* zrow = z + row*DI;
  bf16x8 yv = *(const bf16x8*)(yrow+off);
  bf16x8 zv = *(const bf16x8*)(zrow+off);
  float u[8]; float ss = 0.f;
  #pragma unroll
  for (int e=0;e<8;++e){
    float uu = (float)yv[e]*siluf_((float)zv[e]);
    u[e]=uu; ss += uu*uu;
  }
  #pragma unroll
  for (int o=32;o;o>>=1) ss += __shfl_xor(ss,o);
  if ((tid&63)==0) red[tid>>6] = ss;
  __syncthreads();
  ss = red[sub*2] + red[sub*2+1];
  const float sc = rsqrtf(ss*(1.f/DI) + EPSF);
  const float4* nw4 = (const float4*)(nw + off);
  float4 n0 = nw4[0], n1 = nw4[1];
  bf16x8 o;
  #pragma unroll
  for (int e=0;e<8;++e)
    o[e] = (__bf16)(u[e]*sc*(e<4 ? (&n0.x)[e] : (&n1.x)[e-4]));
  *(bf16x8*)(yrow+off) = o;
}

// ---------------------------------------------------------------------------
__global__ __launch_bounds__(256) void add_ln_k(
    const __bf16* __restrict__ tmp, __bf16* __restrict__ resio,
    const float* __restrict__ w, const float* __restrict__ bb)
{
  const int tid = threadIdx.x, lane = tid&63;
  const size_t row = (size_t)blockIdx.x*4 + (tid>>6);
  const int off = lane*8;
  const __bf16* trow = tmp + row*DM;
  __bf16* rrow = resio + row*DM;
  bf16x8 tv = *(const bf16x8*)(trow+off);
  bf16x8 rv = *(const bf16x8*)(rrow+off);
  float v[8]; float s = 0.f;
  #pragma unroll
  for (int e=0;e<8;++e){ v[e]=(float)tv[e]+(float)rv[e]; s += v[e]; }
  #pragma unroll
  for (int o=32;o;o>>=1) s += __shfl_xor(s,o);
  const float mean = s*(1.f/DM);
  float q = 0.f;
  #pragma unroll
  for (int e=0;e<8;++e){ v[e]-=mean; q += v[e]*v[e]; }
  #pragma unroll
  for (int o=32;o;o>>=1) q += __shfl_xor(q,o);
  const float rstd = rsqrtf(q*(1.f/DM) + EPSF);
  const float4* w4 = (const float4*)(w + off);
  const float4* b4 = (const float4*)(bb + off);
  float4 w0=w4[0], w1=w4[1], b0=b4[0], b1=b4[1];
  bf16x8 o8;
  #pragma unroll
  for (int e=0;e<8;++e){
    float we = e<4 ? (&w0.x)[e] : (&w1.x)[e-4];
    float be = e<4 ? (&b0.x)[e] : (&b1.x)[e-4];
    o8[e] = (__bf16)(v[e]*rstd*we + be);
  }
  *(bf16x8*)(rrow+off) = o8;
}

// ---------------------------------------------------------------------------
extern "C" void kernel_launch(void* const* d_in, const int* in_sizes, int n_in,
                              void* d_out, int out_size, void* d_ws, size_t ws_size,
                              hipStream_t stream)
{
  const float* x         = (const float*)d_in[0];
  const float* in_proj_w = (const float*)d_in[1];
  const float* conv_w    = (const float*)d_in[2];
  const float* conv_b    = (const float*)d_in[3];
  const float* dt_bias   = (const float*)d_in[4];
  const float* A_log     = (const float*)d_in[5];
  const float* Dp        = (const float*)d_in[6];
  const float* norm_w    = (const float*)d_in[7];
  const float* out_proj_w= (const float*)d_in[8];
  const float* ln_w      = (const float*)d_in[9];
  const float* ln_b      = (const float*)d_in[10];
  const float* final_w   = (const float*)d_in[11];
  const float* final_b   = (const float*)d_in[12];
  float* out = (float*)d_out;

  const size_t ROWS = (size_t)BATCH*SEQ;        // 16384
  __bf16* wbf_in  = (__bf16*)d_ws;
  __bf16* wbf_out = wbf_in  + (size_t)NL*DPROJ*DM;
  __bf16* wbf_fin = wbf_out + (size_t)NL*DM*DI;
  __bf16* zbuf    = wbf_fin + (size_t)DM*DM;
  __bf16* xbw     = zbuf    + ROWS*DI;
  __bf16* ybuf    = xbw     + ROWS*XBW;
  __bf16* bcb     = ybuf    + ROWS*DI;
  __bf16* xcur    = bcb     + ROWS*128;
  __bf16* tmp  = xbw;     // alias: xbw dead after ssd_fused reads dt

  {
    int n1 = NL*DPROJ*DM/4, n2 = NL*DM*DI/4, n3 = DM*DM/4, n4 = (int)(ROWS*DM/4);
    int tot = n1+n2+n3+n4;
    cast4_k<<<(tot+255)/256, 256, 0, stream>>>(
        in_proj_w, wbf_in, n1, out_proj_w, wbf_out, n2,
        final_w, wbf_fin, n3, x, xcur, n4);
  }

  const int convTotal = BATCH*SEQ*CSEG;
  const int BIGN = 1<<30;

  for (int l=0; l<NL; ++l){
    const __bf16* wl = wbf_in + (size_t)l*DPROJ*DM;
    // in_proj: grid x = row-tile (XCD A-locality), y = col-tile
    gemm128<__bf16><<<dim3((int)(ROWS/128), (DPROJ+127)/128), 256, 0, stream>>>(
        xcur, wl, zbuf, xbw, nullptr, (int)ROWS, DPROJ, DI, XBW, DI, DM, 0);
    conv_silu_k<<<(convTotal+255)/256, 256, 0, stream>>>(
        xbw, conv_w + (size_t)l*CDIM*4, conv_b + (size_t)l*CDIM, ybuf, bcb);
    ssd_fused_k<<<BATCH*NH, 256, 0, stream>>>(
        bcb, ybuf, xbw, dt_bias + l*NH, A_log + l*NH, Dp + l*NH);
    gate_rms_k<<<(int)(ROWS/2), 256, 0, stream>>>(ybuf, zbuf, norm_w + (size_t)l*DI);
    // out_proj: 128x128 tiles (R10's 64-row variant regressed; reverted)
    gemm128<__bf16><<<dim3((int)(ROWS/128), DM/128), 256, 0, stream>>>(
        ybuf, wbf_out + (size_t)l*DM*DI, tmp, tmp, nullptr, (int)ROWS, DM, DM, DM, BIGN, DI, 0);
    add_ln_k<<<(int)(ROWS/4), 256, 0, stream>>>(tmp, xcur, ln_w + l*DM, ln_b + l*DM);
  }
  // final head: A-rows remapped to the last PREDN timesteps of xcur
  gemm128<float><<<dim3((BATCH*PREDN)/128, DM/128), 256, 0, stream>>>(
      xcur, wbf_fin, out, out, final_b, BATCH*PREDN, DM, DM, DM, BIGN, DM, 1);
}